// Round 1
// 148.120 us; speedup vs baseline: 1.1502x; 1.1502x over previous
//
#include <hip/hip_runtime.h>

#define N_NODES 50000
#define N_EDGES 640000
#define D 128          // D_IN == D_OUT
#define NB 8           // num bases
#define PAD 32         // bucket slots per dst (mean deg 12.8; overflow -> side list)
#define NSTRIP 3125    // 50000 / 16 row-strips

// fused kernel: 1024 blocks, exactly resident at 4 blocks/CU (256 CUs)
#define BUCKET_B 256   // blocks doing edge bucketing
#define GEMM_B   768   // blocks doing the dual GEMM (strip stride)

typedef _Float16 half_t;
typedef __attribute__((ext_vector_type(8))) _Float16 half8;
typedef __attribute__((ext_vector_type(4))) float f32x4;

// ---- k1: zero counters + build Wt/Rt (fp16, transposed [n][k]) ----
__global__ __launch_bounds__(256)
void init_kernel(const float* __restrict__ bases,
                 const float* __restrict__ comp,
                 const float* __restrict__ root,
                 half_t* __restrict__ Wt,
                 half_t* __restrict__ Rt,
                 int* __restrict__ cnt,
                 int* __restrict__ novf) {
    int i = blockIdx.x * 256 + threadIdx.x;
    if (i == 0) *novf = 0;
    if (i < N_NODES) cnt[i] = 0;
    if (i < D * D) {
        int ii = i >> 7, o = i & 127;
        float acc = 0.f;
#pragma unroll
        for (int b = 0; b < NB; ++b)
            acc += comp[b] * bases[((size_t)b * D + ii) * D + o];
        Wt[o * D + ii] = (half_t)acc;
        Rt[o * D + ii] = (half_t)root[i];
    }
}

// ---- k2 (fused): role-split by blockIdx ----
// blocks [0, BUCKET_B): bucket edges (atomic-latency bound, ~no BW)
// blocks [BUCKET_B, BUCKET_B+GEMM_B): y(half)=x@W ; out(f32)=x@root+bias
// Overflow (pos >= PAD) appends (src,dst) to ovf list -- NO y dependency,
// so bucketing overlaps the GEMM instead of serializing after it.
__global__ __launch_bounds__(256, 4)
void fused_kernel(const float* __restrict__ x,
                  const half_t* __restrict__ Wt,   // [n][k]
                  const half_t* __restrict__ Rt,   // [n][k]
                  const float* __restrict__ bias,
                  const int* __restrict__ eidx,
                  half_t* __restrict__ y,
                  float* __restrict__ out,
                  int* __restrict__ cnt,
                  int* __restrict__ bucket,
                  int* __restrict__ ovf,
                  int* __restrict__ novf) {
    const int tid = threadIdx.x;

    if (blockIdx.x < BUCKET_B) {
        // ---------------- bucket role ----------------
        int t = blockIdx.x * 256 + tid;
        for (int e = t; e < N_EDGES; e += BUCKET_B * 256) {
            int src = eidx[e];
            int dst = eidx[N_EDGES + e];
            int pos = atomicAdd(&cnt[dst], 1);
            if (pos < PAD) {
                bucket[(size_t)dst * PAD + pos] = src;
            } else {            // P ~ 1e-7 per node; capacity == N_EDGES, never drops
                int k = atomicAdd(novf, 1);
                ovf[2 * k]     = src;
                ovf[2 * k + 1] = dst;
            }
        }
        return;
    }

    // ---------------- gemm role ----------------
    const int gb   = blockIdx.x - BUCKET_B;  // 0 .. GEMM_B-1
    const int wave = tid >> 6;
    const int lane = tid & 63;
    const int m    = lane & 15;
    const int quad = lane >> 4;
    const int q    = wave;                   // col quarter: nt = 2q, 2q+1
    const int s0   = gb;                     // starting M-strip
    const int SSTR = GEMM_B;

    // B fragments, loaded ONCE: B[k][n], n = lane&15, k = quad*8 + j
    half8 bw[2][4], br[2][4];
    float bb[2];
#pragma unroll
    for (int t = 0; t < 2; ++t) {
        const int nt = 2 * q + t;
        const half_t* wp = Wt + (nt * 16 + m) * D + quad * 8;
        const half_t* rp = Rt + (nt * 16 + m) * D + quad * 8;
#pragma unroll
        for (int kk = 0; kk < 4; ++kk) {
            bw[t][kk] = *(const half8*)(wp + kk * 32);
            br[t][kk] = *(const half8*)(rp + kk * 32);
        }
        bb[t] = bias[nt * 16 + m];
    }

    const float4* x4 = (const float4*)x;
    for (int s = s0; s < NSTRIP; s += SSTR) {
        // A fragment: A[m][k], row = s*16 + m, k = quad*8 + j
        size_t ab = (size_t)(s * 16 + m) * 32 + quad * 2;
        half8 a[4];
#pragma unroll
        for (int kk = 0; kk < 4; ++kk) {
            float4 v0 = x4[ab + kk * 8];
            float4 v1 = x4[ab + kk * 8 + 1];
            half8 h;
            h[0] = (half_t)v0.x; h[1] = (half_t)v0.y; h[2] = (half_t)v0.z; h[3] = (half_t)v0.w;
            h[4] = (half_t)v1.x; h[5] = (half_t)v1.y; h[6] = (half_t)v1.z; h[7] = (half_t)v1.w;
            a[kk] = h;
        }

        f32x4 accW[2], accR[2];
#pragma unroll
        for (int t = 0; t < 2; ++t) {
            accW[t] = (f32x4){0.f, 0.f, 0.f, 0.f};
            accR[t] = (f32x4){0.f, 0.f, 0.f, 0.f};
        }
#pragma unroll
        for (int t = 0; t < 2; ++t)
#pragma unroll
            for (int kk = 0; kk < 4; ++kk) {
                accW[t] = __builtin_amdgcn_mfma_f32_16x16x32_f16(a[kk], bw[t][kk], accW[t], 0, 0, 0);
                accR[t] = __builtin_amdgcn_mfma_f32_16x16x32_f16(a[kk], br[t][kk], accR[t], 0, 0, 0);
            }

        // C/D layout: col = lane&15, row = quad*4 + reg
#pragma unroll
        for (int t = 0; t < 2; ++t) {
            int col = (2 * q + t) * 16 + m;
#pragma unroll
            for (int r = 0; r < 4; ++r) {
                int row = s * 16 + quad * 4 + r;
                y[(size_t)row * D + col]   = (half_t)accW[t][r];
                out[(size_t)row * D + col] = accR[t][r] + bb[t];
            }
        }
    }
}

// ---- k3: gather, 16 lanes per node, 8 rows in flight ----
// Overflowing nodes (cnt > PAD, ~never) scan the ovf side list themselves:
// node-local, no atomics, no ordering hazard vs the non-atomic out RMW.
__global__ __launch_bounds__(256)
void gather_kernel(const int* __restrict__ cnt,
                   const int* __restrict__ bucket,
                   const half_t* __restrict__ y,
                   const int* __restrict__ ovf,
                   const int* __restrict__ novf,
                   float* __restrict__ out) {
    int node = blockIdx.x * 16 + (threadIdx.x >> 4);
    int q = threadIdx.x & 15;
    if (node >= N_NODES) return;
    int c_raw = cnt[node];
    int c = c_raw > PAD ? PAD : c_raw;
    const int* b = bucket + (size_t)node * PAD;
    float acc[8] = {0.f, 0.f, 0.f, 0.f, 0.f, 0.f, 0.f, 0.f};
    int i = 0;
    for (; i + 8 <= c; i += 8) {
        int4 s0 = *(const int4*)(b + i);
        int4 s1 = *(const int4*)(b + i + 4);
        half8 v0 = *(const half8*)(y + (size_t)s0.x * D + q * 8);
        half8 v1 = *(const half8*)(y + (size_t)s0.y * D + q * 8);
        half8 v2 = *(const half8*)(y + (size_t)s0.z * D + q * 8);
        half8 v3 = *(const half8*)(y + (size_t)s0.w * D + q * 8);
        half8 v4 = *(const half8*)(y + (size_t)s1.x * D + q * 8);
        half8 v5 = *(const half8*)(y + (size_t)s1.y * D + q * 8);
        half8 v6 = *(const half8*)(y + (size_t)s1.z * D + q * 8);
        half8 v7 = *(const half8*)(y + (size_t)s1.w * D + q * 8);
#pragma unroll
        for (int j = 0; j < 8; ++j)
            acc[j] += ((float)v0[j] + (float)v1[j]) + ((float)v2[j] + (float)v3[j])
                    + ((float)v4[j] + (float)v5[j]) + ((float)v6[j] + (float)v7[j]);
    }
    for (; i + 4 <= c; i += 4) {
        int4 s = *(const int4*)(b + i);
        half8 v0 = *(const half8*)(y + (size_t)s.x * D + q * 8);
        half8 v1 = *(const half8*)(y + (size_t)s.y * D + q * 8);
        half8 v2 = *(const half8*)(y + (size_t)s.z * D + q * 8);
        half8 v3 = *(const half8*)(y + (size_t)s.w * D + q * 8);
#pragma unroll
        for (int j = 0; j < 8; ++j)
            acc[j] += ((float)v0[j] + (float)v1[j]) + ((float)v2[j] + (float)v3[j]);
    }
    for (; i < c; ++i) {
        half8 v = *(const half8*)(y + (size_t)b[i] * D + q * 8);
#pragma unroll
        for (int j = 0; j < 8; ++j) acc[j] += (float)v[j];
    }
    if (c_raw > PAD) {             // rare path: scan side list for this node's extras
        int n = *novf;
        for (int k = 0; k < n; ++k) {
            if (ovf[2 * k + 1] == node) {
                half8 v = *(const half8*)(y + (size_t)ovf[2 * k] * D + q * 8);
#pragma unroll
                for (int j = 0; j < 8; ++j) acc[j] += (float)v[j];
            }
        }
    }
    float4* op = (float4*)(out + (size_t)node * D + q * 8);
    float4 o0 = op[0], o1 = op[1];
    o0.x += acc[0]; o0.y += acc[1]; o0.z += acc[2]; o0.w += acc[3];
    o1.x += acc[4]; o1.y += acc[5]; o1.z += acc[6]; o1.w += acc[7];
    op[0] = o0; op[1] = o1;
}

extern "C" void kernel_launch(void* const* d_in, const int* in_sizes, int n_in,
                              void* d_out, int out_size, void* d_ws, size_t ws_size,
                              hipStream_t stream) {
    const float* x     = (const float*)d_in[0];
    const int*   eidx  = (const int*)d_in[1];
    const float* bases = (const float*)d_in[2];
    const float* comp  = (const float*)d_in[3];
    const float* root  = (const float*)d_in[4];
    const float* bias  = (const float*)d_in[5];
    float* out = (float*)d_out;

    char* ws = (char*)d_ws;
    half_t* y      = (half_t*)ws;                      // 12,800,000 B
    half_t* Wt     = (half_t*)(ws + 12800000);         //     32,768 B
    half_t* Rt     = (half_t*)(ws + 12832768);         //     32,768 B
    int*    cnt    = (int*)   (ws + 12865536);         //    200,000 B
    int*    bucket = (int*)   (ws + 13065536);         //  6,400,000 B
    int*    novf   = (int*)   (ws + 19465536);         //         16 B
    int*    ovf    = (int*)   (ws + 19465552);         //  5,120,000 B (capacity == E)

    init_kernel<<<(N_NODES + 255) / 256, 256, 0, stream>>>(
        bases, comp, root, Wt, Rt, cnt, novf);
    fused_kernel<<<BUCKET_B + GEMM_B, 256, 0, stream>>>(
        x, Wt, Rt, bias, eidx, y, out, cnt, bucket, ovf, novf);
    gather_kernel<<<(N_NODES + 15) / 16, 256, 0, stream>>>(
        cnt, bucket, y, ovf, novf, out);
}